// Round 6
// baseline (1034.500 us; speedup 1.0000x reference)
//
#include <hip/hip_runtime.h>
#include <math.h>

// Problem constants
#define BB    64        // batch
#define NEC   40000     // num entities
#define NRC   500       // num relations
#define D1C   200
#define D2C   200
#define LLC   64        // literals
#define BN_EPS 1e-5f
#define LOG2E 1.4426950408889634f

// ws layout (floats):
//   xT   [D1][64]   @ 0       (bn0 output, transposed: xT[i*64+b])
//   rT   [D2][64]   @ 12800   (gathered relation rows, rT[k*64+b])
//   taT  [L ][64]   @ 25600   (2*(n_h - c)*s, transposed)
//   wT   [L ][64]   @ 29696   (nf[r] * exp2(-a^2), transposed)
//   sl   [L ]       @ 33792   (s[l] = sqrt(log2e/var_l[l]))
//   x2T  [D1][64]   @ 33856   (bn1 output, transposed)
//   y    [k][j][64] @ 46656   (per-k partials, r folded in)
#define WS_XT   0
#define WS_RT   12800
#define WS_AT   25600
#define WS_WT   29696
#define WS_SL   33792
#define WS_X2T  33856
#define WS_Y    46656

// ---------------------------------------------------------------------------
// Kernel A: gathers + bn0 + literal pre-transforms. Tiny; 3 blocks.
// ---------------------------------------------------------------------------
__global__ __launch_bounds__(256) void prep_kernel(
    const int* __restrict__ e1_idx, const int* __restrict__ r_idx,
    const float* __restrict__ E, const float* __restrict__ R,
    const float* __restrict__ lits, const float* __restrict__ c,
    const float* __restrict__ var_l, const float* __restrict__ nf,
    const float* __restrict__ bn0g, const float* __restrict__ bn0b,
    float* __restrict__ ws) {
  float* xT  = ws + WS_XT;
  float* rT  = ws + WS_RT;
  float* taT = ws + WS_AT;
  float* wT  = ws + WS_WT;
  float* sl  = ws + WS_SL;
  int tid = threadIdx.x;

  if (blockIdx.x == 0) {
    if (tid < D1C) {
      int j = tid;
      float sum = 0.f, sq = 0.f;
      for (int b = 0; b < BB; b++) {
        float e = E[e1_idx[b] * D1C + j];
        sum += e; sq += e * e;
      }
      float mean = sum * (1.f / 64.f);
      float var  = sq  * (1.f / 64.f) - mean * mean;
      float inv  = __builtin_amdgcn_rsqf(var + BN_EPS);
      float g    = bn0g[j] * inv;
      float be   = bn0b[j] - mean * g;
      for (int b = 0; b < BB; b++) {
        xT[j * 64 + b] = g * E[e1_idx[b] * D1C + j] + be;
      }
    }
  } else if (blockIdx.x == 1) {
    for (int idx = tid; idx < D2C * 64; idx += 256) {
      int k = idx >> 6, b = idx & 63;
      rT[idx] = R[r_idx[b] * D2C + k];
    }
  } else {
    // w*exp2(-(a-L)^2) = [w*exp2(-a^2)] * exp2(fma(2a, L, -L^2))
    for (int idx = tid; idx < LLC * 64; idx += 256) {
      int l = idx >> 6, b = idx & 63;
      float s = sqrtf(LOG2E / var_l[l]);
      float a = (lits[e1_idx[b] * LLC + l] - c[l]) * s;
      taT[idx] = a + a;
      wT[idx]  = nf[r_idx[b] * LLC + l] * __builtin_amdgcn_exp2f(-a * a);
    }
    if (tid < LLC) sl[tid] = sqrtf(LOG2E / var_l[tid]);
  }
}

// ---------------------------------------------------------------------------
// Stage 1 (unchanged R2 config, measured cheapest middle).
// ---------------------------------------------------------------------------
__global__ __launch_bounds__(128) void stage1_kernel(
    const float* __restrict__ W, const float* __restrict__ ws_in,
    float* __restrict__ y) {
  const float* xT = ws_in + WS_XT;
  const float* rT = ws_in + WS_RT;
  int k = blockIdx.x, jq = blockIdx.y;
  int lane = threadIdx.x & 63;
  int wid = __builtin_amdgcn_readfirstlane(threadIdx.x >> 6);
  int j0 = jq * 20 + wid * 10;

  float r = rT[k * 64 + lane];
  float acc[10];
#pragma unroll
  for (int jj = 0; jj < 10; jj++) acc[jj] = 0.f;

  const float* Wk = W + (k * D1C) * D1C + j0;
  for (int i = 0; i < D1C; i++) {
    float xv = xT[i * 64 + lane];
    const float* wr = Wk + i * D1C;
#pragma unroll
    for (int jj = 0; jj < 10; jj++) acc[jj] += xv * wr[jj];
  }

  float* yo = y + (k * D1C + j0) * 64 + lane;
#pragma unroll
  for (int jj = 0; jj < 10; jj++) yo[jj * 64] = r * acc[jj];
}

// ---------------------------------------------------------------------------
// Kernel C (unchanged): reduce y over k, bn1 over b -> x2T[j][b]
// ---------------------------------------------------------------------------
__global__ __launch_bounds__(256) void reduce_bn1_kernel(
    const float* __restrict__ y, const float* __restrict__ bn1g,
    const float* __restrict__ bn1b, float* __restrict__ ws) {
  float* x2T = ws + WS_X2T;
  int j = blockIdx.x;
  int tid = threadIdx.x, b = tid & 63, kq = tid >> 6;

  float s = 0.f;
  const float* yp = y + (kq * 50 * D1C + j) * 64 + b;
  for (int k = 0; k < 50; k++) s += yp[k * D1C * 64];

  __shared__ float part[256];
  part[tid] = s;
  __syncthreads();
  if (tid < 64) {
    float v = part[tid] + part[64 + tid] + part[128 + tid] + part[192 + tid];
    float sum = v, sq = v * v;
#pragma unroll
    for (int o = 32; o > 0; o >>= 1) {
      sum += __shfl_xor(sum, o, 64);
      sq  += __shfl_xor(sq,  o, 64);
    }
    float mean = sum * (1.f / 64.f);
    float var  = sq  * (1.f / 64.f) - mean * mean;
    float inv  = __builtin_amdgcn_rsqf(var + BN_EPS);
    float g    = bn1g[j] * inv;
    float be   = bn1b[j] - mean * g;
    x2T[j * 64 + tid] = g * v + be;
  }
}

// ---------------------------------------------------------------------------
// Final: out[b,n] = sigmoid( sum_j x2[b,j]E[n,j]
//                          + sum_l w'[b,l]*exp2(fma(2a[b,l], L[n,l], -L^2)) )
// grid 625, 256 thr = 4 waves x 16-b acc (R4 config — clean-traffic regime).
// KEY CHANGES vs R4:
//  * xw/aw/ww read via per-lane VMEM broadcast (laundered divergent base) so
//    the hot loops never mix SMEM with DS on lgkmcnt -> no lgkmcnt(0) drains.
//  * explicit depth-2 register double-buffers for those streams (vmcnt-
//    pipelined independently of the ds_read stream).
//  * global->LDS staging via registers: loads issued BEFORE the j-loop,
//    ds_write AFTER it -> vmcnt wait sits behind ~7k cycles of FMA.
// ---------------------------------------------------------------------------
__global__ __launch_bounds__(256, 4) void final_kernel(
    const float* __restrict__ E, const float* __restrict__ lits,
    const float* __restrict__ ws, float* __restrict__ out) {
  const float* taT = ws + WS_AT;
  const float* wT  = ws + WS_WT;
  const float* sl  = ws + WS_SL;
  const float* x2T = ws + WS_X2T;

  __shared__ float Sa[64 * 65];
  __shared__ float Sb[64 * 65];

  int n0 = blockIdx.x * 64;
  int tid = threadIdx.x;
  int lane = tid & 63;
  int boff = __builtin_amdgcn_readfirstlane(tid >> 6) * 16;

  // Laundered zero: opaque VGPR value so the following bases look divergent
  // and LLVM emits VMEM (vmcnt) loads instead of s_load (lgkmcnt).
  int lzero;
  asm volatile("v_mov_b32 %0, 0" : "=v"(lzero));
  const float* x2d = x2T + lzero;
  const float* tad = taT + lzero;
  const float* wwd = wT  + lzero;

  // E tile staging: 1600 float2 items -> regs -> (later) LDS col-major [j][row]
  float2 er[7];
  auto loadE = [&](int q) {
#pragma unroll
    for (int it = 0; it < 7; it++) {
      int idx = tid + it * 256;
      if (idx < 1600) {
        int row = idx / 25, c2 = idx % 25;
        er[it] = *(const float2*)(E + (n0 + row) * D1C + q * 50 + c2 * 2);
      }
    }
  };
  auto writeE = [&](float* S) {
#pragma unroll
    for (int it = 0; it < 7; it++) {
      int idx = tid + it * 256;
      if (idx < 1600) {
        int row = idx / 25, c2 = idx % 25;
        S[(c2 * 2 + 0) * 65 + row] = er[it].x;
        S[(c2 * 2 + 1) * 65 + row] = er[it].y;
      }
    }
  };

  float acc[16];
#pragma unroll
  for (int bb = 0; bb < 16; bb++) acc[bb] = 0.f;

  loadE(0);
  writeE(Sa);
  __syncthreads();

  float4 lr[4];   // lits tile registers (used at q==3)

#pragma unroll
  for (int q = 0; q < 4; q++) {
    float* cur = (q & 1) ? Sb : Sa;
    float* nxt = (q & 1) ? Sa : Sb;
    if (q < 3) {
      loadE(q + 1);
    } else {
#pragma unroll
      for (int it = 0; it < 4; it++) {
        int idx = tid + it * 256;
        int row = idx >> 4, c4 = idx & 15;
        lr[it] = *(const float4*)(lits + (n0 + row) * LLC + c4 * 4);
      }
    }

    // ---- 50-j GEMM slab: ev from LDS (lgkm), xw from VMEM (vmcnt) ----
    const float4* xq = (const float4*)(x2d + q * 3200 + boff);
    float4 xa[4], xb[4];
#pragma unroll
    for (int t = 0; t < 4; t++) xa[t] = xq[t];
    for (int j = 0; j < 50; j += 2) {
#pragma unroll
      for (int t = 0; t < 4; t++) xb[t] = xq[(j + 1) * 16 + t];
      float ev0 = cur[j * 65 + lane];
#pragma unroll
      for (int t = 0; t < 4; t++) {
        acc[t * 4 + 0] += ev0 * xa[t].x;
        acc[t * 4 + 1] += ev0 * xa[t].y;
        acc[t * 4 + 2] += ev0 * xa[t].z;
        acc[t * 4 + 3] += ev0 * xa[t].w;
      }
#pragma unroll
      for (int t = 0; t < 4; t++) xa[t] = xq[(j + 2) * 16 + t]; // j=48: benign overread into ws
      float ev1 = cur[(j + 1) * 65 + lane];
#pragma unroll
      for (int t = 0; t < 4; t++) {
        acc[t * 4 + 0] += ev1 * xb[t].x;
        acc[t * 4 + 1] += ev1 * xb[t].y;
        acc[t * 4 + 2] += ev1 * xb[t].z;
        acc[t * 4 + 3] += ev1 * xb[t].w;
      }
    }

    if (q < 3) {
      writeE(nxt);
    } else {
      // scaled literals, col-major: S[l][row]
#pragma unroll
      for (int it = 0; it < 4; it++) {
        int idx = tid + it * 256;
        int row = idx >> 4, c4 = idx & 15;
        int l = c4 * 4;
        nxt[(l + 0) * 65 + row] = lr[it].x * sl[l + 0];
        nxt[(l + 1) * 65 + row] = lr[it].y * sl[l + 1];
        nxt[(l + 2) * 65 + row] = lr[it].z * sl[l + 2];
        nxt[(l + 3) * 65 + row] = lr[it].w * sl[l + 3];
      }
    }
    __syncthreads();
  }

  // ---- score_n: L from LDS (lgkm), 2a/w' from VMEM (vmcnt), depth-2 ----
  const float4* aq = (const float4*)(tad + boff);
  const float4* wq = (const float4*)(wwd + boff);
  float4 aA[4], wA[4], aB[4], wB[4];
#pragma unroll
  for (int t = 0; t < 4; t++) { aA[t] = aq[t]; wA[t] = wq[t]; }
  for (int l = 0; l < LLC; l += 2) {
#pragma unroll
    for (int t = 0; t < 4; t++) {
      aB[t] = aq[(l + 1) * 16 + t];
      wB[t] = wq[(l + 1) * 16 + t];
    }
    float L0 = Sa[l * 65 + lane];
    float nl0 = -L0 * L0;
#pragma unroll
    for (int t = 0; t < 4; t++) {
      acc[t * 4 + 0] += wA[t].x * __builtin_amdgcn_exp2f(__builtin_fmaf(aA[t].x, L0, nl0));
      acc[t * 4 + 1] += wA[t].y * __builtin_amdgcn_exp2f(__builtin_fmaf(aA[t].y, L0, nl0));
      acc[t * 4 + 2] += wA[t].z * __builtin_amdgcn_exp2f(__builtin_fmaf(aA[t].z, L0, nl0));
      acc[t * 4 + 3] += wA[t].w * __builtin_amdgcn_exp2f(__builtin_fmaf(aA[t].w, L0, nl0));
    }
#pragma unroll
    for (int t = 0; t < 4; t++) {       // l=62: benign overread into ws
      aA[t] = aq[(l + 2) * 16 + t];
      wA[t] = wq[(l + 2) * 16 + t];
    }
    float L1 = Sa[(l + 1) * 65 + lane];
    float nl1 = -L1 * L1;
#pragma unroll
    for (int t = 0; t < 4; t++) {
      acc[t * 4 + 0] += wB[t].x * __builtin_amdgcn_exp2f(__builtin_fmaf(aB[t].x, L1, nl1));
      acc[t * 4 + 1] += wB[t].y * __builtin_amdgcn_exp2f(__builtin_fmaf(aB[t].y, L1, nl1));
      acc[t * 4 + 2] += wB[t].z * __builtin_amdgcn_exp2f(__builtin_fmaf(aB[t].z, L1, nl1));
      acc[t * 4 + 3] += wB[t].w * __builtin_amdgcn_exp2f(__builtin_fmaf(aB[t].w, L1, nl1));
    }
  }

  // ---- sigmoid + coalesced store ----
#pragma unroll
  for (int bb = 0; bb < 16; bb++) {
    float s = acc[bb];
    float e = __builtin_amdgcn_exp2f(-LOG2E * s);
    out[(boff + bb) * NEC + n0 + lane] = __builtin_amdgcn_rcpf(1.f + e);
  }
}

// ---------------------------------------------------------------------------
extern "C" void kernel_launch(void* const* d_in, const int* in_sizes, int n_in,
                              void* d_out, int out_size, void* d_ws, size_t ws_size,
                              hipStream_t stream) {
  (void)in_sizes; (void)n_in; (void)out_size; (void)ws_size;
  const int*   e1    = (const int*)d_in[0];
  const int*   ri    = (const int*)d_in[1];
  const float* E     = (const float*)d_in[2];
  const float* R     = (const float*)d_in[3];
  const float* W     = (const float*)d_in[4];
  const float* lits  = (const float*)d_in[5];
  const float* c     = (const float*)d_in[6];
  const float* var_l = (const float*)d_in[7];
  const float* nf    = (const float*)d_in[8];
  const float* bn0g  = (const float*)d_in[9];
  const float* bn0b  = (const float*)d_in[10];
  const float* bn1g  = (const float*)d_in[11];
  const float* bn1b  = (const float*)d_in[12];
  float* out = (float*)d_out;
  float* ws  = (float*)d_ws;
  float* y   = ws + WS_Y;

  prep_kernel<<<3, 256, 0, stream>>>(e1, ri, E, R, lits, c, var_l, nf,
                                     bn0g, bn0b, ws);
  stage1_kernel<<<dim3(200, 10), 128, 0, stream>>>(W, ws, y);
  reduce_bn1_kernel<<<200, 256, 0, stream>>>(y, bn1g, bn1b, ws);
  final_kernel<<<625, 256, 0, stream>>>(E, lits, ws, out);
}

// Round 7
// 240.380 us; speedup vs baseline: 4.3036x; 4.3036x over previous
//
#include <hip/hip_runtime.h>
#include <math.h>

// Problem constants
#define BB    64        // batch
#define NEC   40000     // num entities
#define NRC   500       // num relations
#define D1C   200
#define D2C   200
#define LLC   64        // literals
#define BN_EPS 1e-5f
#define LOG2E 1.4426950408889634f

// ws layout (floats):
//   xT   [D1][64]   @ 0       (bn0 output, transposed: xT[i*64+b])
//   rT   [D2][64]   @ 12800   (gathered relation rows, rT[k*64+b])
//   taT  [L ][64]   @ 25600   (2*(n_h - c)*s, transposed)
//   wT   [L ][64]   @ 29696   (nf[r] * exp2(-a^2), transposed)
//   sl   [L ]       @ 33792   (s[l] = sqrt(log2e/var_l[l]))
//   x2T  [D1][64]   @ 33856   (bn1 output, transposed)
//   y    [k][j][64] @ 46656   (per-k partials, r folded in)
#define WS_XT   0
#define WS_RT   12800
#define WS_AT   25600
#define WS_WT   29696
#define WS_SL   33792
#define WS_X2T  33856
#define WS_Y    46656

// ---------------------------------------------------------------------------
// Kernel A: gathers + bn0 + literal pre-transforms. Tiny; 3 blocks.
// ---------------------------------------------------------------------------
__global__ __launch_bounds__(256) void prep_kernel(
    const int* __restrict__ e1_idx, const int* __restrict__ r_idx,
    const float* __restrict__ E, const float* __restrict__ R,
    const float* __restrict__ lits, const float* __restrict__ c,
    const float* __restrict__ var_l, const float* __restrict__ nf,
    const float* __restrict__ bn0g, const float* __restrict__ bn0b,
    float* __restrict__ ws) {
  float* xT  = ws + WS_XT;
  float* rT  = ws + WS_RT;
  float* taT = ws + WS_AT;
  float* wT  = ws + WS_WT;
  float* sl  = ws + WS_SL;
  int tid = threadIdx.x;

  if (blockIdx.x == 0) {
    if (tid < D1C) {
      int j = tid;
      float sum = 0.f, sq = 0.f;
      for (int b = 0; b < BB; b++) {
        float e = E[e1_idx[b] * D1C + j];
        sum += e; sq += e * e;
      }
      float mean = sum * (1.f / 64.f);
      float var  = sq  * (1.f / 64.f) - mean * mean;
      float inv  = __builtin_amdgcn_rsqf(var + BN_EPS);
      float g    = bn0g[j] * inv;
      float be   = bn0b[j] - mean * g;
      for (int b = 0; b < BB; b++) {
        xT[j * 64 + b] = g * E[e1_idx[b] * D1C + j] + be;
      }
    }
  } else if (blockIdx.x == 1) {
    for (int idx = tid; idx < D2C * 64; idx += 256) {
      int k = idx >> 6, b = idx & 63;
      rT[idx] = R[r_idx[b] * D2C + k];
    }
  } else {
    // w*exp2(-(a-L)^2) = [w*exp2(-a^2)] * exp2(fma(2a, L, -L^2))
    for (int idx = tid; idx < LLC * 64; idx += 256) {
      int l = idx >> 6, b = idx & 63;
      float s = sqrtf(LOG2E / var_l[l]);
      float a = (lits[e1_idx[b] * LLC + l] - c[l]) * s;
      taT[idx] = a + a;
      wT[idx]  = nf[r_idx[b] * LLC + l] * __builtin_amdgcn_exp2f(-a * a);
    }
    if (tid < LLC) sl[tid] = sqrtf(LOG2E / var_l[tid]);
  }
}

// ---------------------------------------------------------------------------
// Stage 1 (unchanged R2 config, measured cheapest middle).
// ---------------------------------------------------------------------------
__global__ __launch_bounds__(128) void stage1_kernel(
    const float* __restrict__ W, const float* __restrict__ ws_in,
    float* __restrict__ y) {
  const float* xT = ws_in + WS_XT;
  const float* rT = ws_in + WS_RT;
  int k = blockIdx.x, jq = blockIdx.y;
  int lane = threadIdx.x & 63;
  int wid = __builtin_amdgcn_readfirstlane(threadIdx.x >> 6);
  int j0 = jq * 20 + wid * 10;

  float r = rT[k * 64 + lane];
  float acc[10];
#pragma unroll
  for (int jj = 0; jj < 10; jj++) acc[jj] = 0.f;

  const float* Wk = W + (k * D1C) * D1C + j0;
  for (int i = 0; i < D1C; i++) {
    float xv = xT[i * 64 + lane];
    const float* wr = Wk + i * D1C;
#pragma unroll
    for (int jj = 0; jj < 10; jj++) acc[jj] += xv * wr[jj];
  }

  float* yo = y + (k * D1C + j0) * 64 + lane;
#pragma unroll
  for (int jj = 0; jj < 10; jj++) yo[jj * 64] = r * acc[jj];
}

// ---------------------------------------------------------------------------
// Kernel C (unchanged): reduce y over k, bn1 over b -> x2T[j][b]
// ---------------------------------------------------------------------------
__global__ __launch_bounds__(256) void reduce_bn1_kernel(
    const float* __restrict__ y, const float* __restrict__ bn1g,
    const float* __restrict__ bn1b, float* __restrict__ ws) {
  float* x2T = ws + WS_X2T;
  int j = blockIdx.x;
  int tid = threadIdx.x, b = tid & 63, kq = tid >> 6;

  float s = 0.f;
  const float* yp = y + (kq * 50 * D1C + j) * 64 + b;
  for (int k = 0; k < 50; k++) s += yp[k * D1C * 64];

  __shared__ float part[256];
  part[tid] = s;
  __syncthreads();
  if (tid < 64) {
    float v = part[tid] + part[64 + tid] + part[128 + tid] + part[192 + tid];
    float sum = v, sq = v * v;
#pragma unroll
    for (int o = 32; o > 0; o >>= 1) {
      sum += __shfl_xor(sum, o, 64);
      sq  += __shfl_xor(sq,  o, 64);
    }
    float mean = sum * (1.f / 64.f);
    float var  = sq  * (1.f / 64.f) - mean * mean;
    float inv  = __builtin_amdgcn_rsqf(var + BN_EPS);
    float g    = bn1g[j] * inv;
    float be   = bn1b[j] - mean * g;
    x2T[j * 64 + tid] = g * v + be;
  }
}

// ---------------------------------------------------------------------------
// Final: out[b,n] = sigmoid( sum_j x2[b,j]E[n,j]
//                          + sum_l w'[b,l]*exp2(fma(2a[b,l], L[n,l], -L^2)) )
// grid 625, 256 thr = 4 waves x 16-b acc (R4 shape).
// ALL hot-loop operands come from LDS (DS is in-order on lgkmcnt, so the
// compiler can pipeline with partial lgkmcnt(N) waits instead of the full
// drains forced by mixing s_load+ds_read):
//  * E tile (per-lane reads)  : Sa/Sb double-buffer, as in R4.
//  * x2 quarter (broadcasts)  : Sc double-buffer, staged alongside E.
//  * ta/w (broadcasts)        : staged into idle Sb in two halves.
// Wave-uniform LDS reads are same-address broadcasts -> conflict-free.
// ---------------------------------------------------------------------------
__global__ __launch_bounds__(256, 4) void final_kernel(
    const float* __restrict__ E, const float* __restrict__ lits,
    const float* __restrict__ ws, float* __restrict__ out) {
  const float* taT = ws + WS_AT;
  const float* wT  = ws + WS_WT;
  const float* sl  = ws + WS_SL;
  const float* x2T = ws + WS_X2T;

  __shared__ float Sa[64 * 65];      // E quarter [50][65] / lits [64][65]
  __shared__ float Sb[64 * 65];      // E quarter / ta+w halves (2048+2048)
  __shared__ float Sc[2][50 * 64];   // x2 quarter double-buffer [j][b]

  int n0 = blockIdx.x * 64;
  int tid = threadIdx.x;
  int lane = tid & 63;
  int boff = __builtin_amdgcn_readfirstlane(tid >> 6) * 16;

  // stage E quarter q transposed: S[j_local*65 + row]  (65: write-side pad)
  auto stageE = [&](float* S, int q) {
    for (int idx = tid; idx < 64 * 25; idx += 256) {
      int row = idx / 25, c2 = idx % 25;
      const float2 v = *(const float2*)(E + (n0 + row) * D1C + q * 50 + c2 * 2);
      S[(c2 * 2 + 0) * 65 + row] = v.x;
      S[(c2 * 2 + 1) * 65 + row] = v.y;
    }
  };
  // stage x2 quarter q: straight 3200-float copy (coalesced float4)
  auto stageX = [&](float* S, int q) {
    const float4* src = (const float4*)(x2T + q * 3200);
    float4* dst = (float4*)S;
    for (int idx = tid; idx < 800; idx += 256) dst[idx] = src[idx];
  };

  float acc[16];
#pragma unroll
  for (int bb = 0; bb < 16; bb++) acc[bb] = 0.f;

  stageE(Sa, 0);
  stageX(Sc[0], 0);
  __syncthreads();

#pragma unroll
  for (int q = 0; q < 4; q++) {
    float* cur  = (q & 1) ? Sb : Sa;
    float* nxt  = (q & 1) ? Sa : Sb;
    float* curC = Sc[q & 1];
    float* nxtC = Sc[(q + 1) & 1];
    if (q < 3) {
      stageE(nxt, q + 1);
      stageX(nxtC, q + 1);
    } else {
      // stage scaled literals L = lit*s into the idle buffer (Sa)
      for (int idx = tid; idx < 64 * 16; idx += 256) {
        int row = idx >> 4, c4 = idx & 15;
        const float4 v = *(const float4*)(lits + (n0 + row) * LLC + c4 * 4);
        int l = c4 * 4;
        nxt[(l + 0) * 65 + row] = v.x * sl[l + 0];
        nxt[(l + 1) * 65 + row] = v.y * sl[l + 1];
        nxt[(l + 2) * 65 + row] = v.z * sl[l + 2];
        nxt[(l + 3) * 65 + row] = v.w * sl[l + 3];
      }
    }
    // ---- 50-j slab: ev per-lane ds_read; xw broadcast ds_read_b128 ----
    for (int j = 0; j < 50; j++) {
      float ev = cur[j * 65 + lane];
      const float4* xw4 = (const float4*)(curC + j * 64 + boff);
      float4 x0 = xw4[0], x1 = xw4[1], x2v = xw4[2], x3 = xw4[3];
      acc[ 0] += ev * x0.x;  acc[ 1] += ev * x0.y;
      acc[ 2] += ev * x0.z;  acc[ 3] += ev * x0.w;
      acc[ 4] += ev * x1.x;  acc[ 5] += ev * x1.y;
      acc[ 6] += ev * x1.z;  acc[ 7] += ev * x1.w;
      acc[ 8] += ev * x2v.x; acc[ 9] += ev * x2v.y;
      acc[10] += ev * x2v.z; acc[11] += ev * x2v.w;
      acc[12] += ev * x3.x;  acc[13] += ev * x3.y;
      acc[14] += ev * x3.z;  acc[15] += ev * x3.w;
    }
    __syncthreads();
  }

  // ---- score_n: lits from Sa (per-lane), ta/w from Sb (broadcast) ----
  for (int h = 0; h < 2; h++) {
    if (h) __syncthreads();           // protect Sb restage
    {                                  // stage half h: ta -> Sb[0:2048), w -> Sb[2048:4096)
      const float4* ta4 = (const float4*)(taT + h * 2048);
      const float4* w4s = (const float4*)(wT + h * 2048);
      float4* dst = (float4*)Sb;
      for (int idx = tid; idx < 512; idx += 256) {
        dst[idx]       = ta4[idx];
        dst[512 + idx] = w4s[idx];
      }
    }
    __syncthreads();
    for (int ll = 0; ll < 32; ll++) {
      float L = Sa[(h * 32 + ll) * 65 + lane];
      float nl2 = -L * L;
      const float4* a4 = (const float4*)(Sb + ll * 64 + boff);
      const float4* w4 = (const float4*)(Sb + 2048 + ll * 64 + boff);
      float4 a0 = a4[0], a1 = a4[1], a2 = a4[2], a3 = a4[3];
      float4 w0 = w4[0], w1 = w4[1], w2 = w4[2], w3 = w4[3];
      acc[ 0] += w0.x * __builtin_amdgcn_exp2f(__builtin_fmaf(a0.x, L, nl2));
      acc[ 1] += w0.y * __builtin_amdgcn_exp2f(__builtin_fmaf(a0.y, L, nl2));
      acc[ 2] += w0.z * __builtin_amdgcn_exp2f(__builtin_fmaf(a0.z, L, nl2));
      acc[ 3] += w0.w * __builtin_amdgcn_exp2f(__builtin_fmaf(a0.w, L, nl2));
      acc[ 4] += w1.x * __builtin_amdgcn_exp2f(__builtin_fmaf(a1.x, L, nl2));
      acc[ 5] += w1.y * __builtin_amdgcn_exp2f(__builtin_fmaf(a1.y, L, nl2));
      acc[ 6] += w1.z * __builtin_amdgcn_exp2f(__builtin_fmaf(a1.z, L, nl2));
      acc[ 7] += w1.w * __builtin_amdgcn_exp2f(__builtin_fmaf(a1.w, L, nl2));
      acc[ 8] += w2.x * __builtin_amdgcn_exp2f(__builtin_fmaf(a2.x, L, nl2));
      acc[ 9] += w2.y * __builtin_amdgcn_exp2f(__builtin_fmaf(a2.y, L, nl2));
      acc[10] += w2.z * __builtin_amdgcn_exp2f(__builtin_fmaf(a2.z, L, nl2));
      acc[11] += w2.w * __builtin_amdgcn_exp2f(__builtin_fmaf(a2.w, L, nl2));
      acc[12] += w3.x * __builtin_amdgcn_exp2f(__builtin_fmaf(a3.x, L, nl2));
      acc[13] += w3.y * __builtin_amdgcn_exp2f(__builtin_fmaf(a3.y, L, nl2));
      acc[14] += w3.z * __builtin_amdgcn_exp2f(__builtin_fmaf(a3.z, L, nl2));
      acc[15] += w3.w * __builtin_amdgcn_exp2f(__builtin_fmaf(a3.w, L, nl2));
    }
  }

  // ---- sigmoid + coalesced store ----
#pragma unroll
  for (int bb = 0; bb < 16; bb++) {
    float s = acc[bb];
    float e = __builtin_amdgcn_exp2f(-LOG2E * s);
    out[(boff + bb) * NEC + n0 + lane] = __builtin_amdgcn_rcpf(1.f + e);
  }
}

// ---------------------------------------------------------------------------
extern "C" void kernel_launch(void* const* d_in, const int* in_sizes, int n_in,
                              void* d_out, int out_size, void* d_ws, size_t ws_size,
                              hipStream_t stream) {
  (void)in_sizes; (void)n_in; (void)out_size; (void)ws_size;
  const int*   e1    = (const int*)d_in[0];
  const int*   ri    = (const int*)d_in[1];
  const float* E     = (const float*)d_in[2];
  const float* R     = (const float*)d_in[3];
  const float* W     = (const float*)d_in[4];
  const float* lits  = (const float*)d_in[5];
  const float* c     = (const float*)d_in[6];
  const float* var_l = (const float*)d_in[7];
  const float* nf    = (const float*)d_in[8];
  const float* bn0g  = (const float*)d_in[9];
  const float* bn0b  = (const float*)d_in[10];
  const float* bn1g  = (const float*)d_in[11];
  const float* bn1b  = (const float*)d_in[12];
  float* out = (float*)d_out;
  float* ws  = (float*)d_ws;
  float* y   = ws + WS_Y;

  prep_kernel<<<3, 256, 0, stream>>>(e1, ri, E, R, lits, c, var_l, nf,
                                     bn0g, bn0b, ws);
  stage1_kernel<<<dim3(200, 10), 128, 0, stream>>>(W, ws, y);
  reduce_bn1_kernel<<<200, 256, 0, stream>>>(y, bn1g, bn1b, ws);
  final_kernel<<<625, 256, 0, stream>>>(E, lits, ws, out);
}

// Round 8
// 223.580 us; speedup vs baseline: 4.6270x; 1.0751x over previous
//
#include <hip/hip_runtime.h>
#include <math.h>

// Problem constants
#define BB    64        // batch
#define NEC   40000     // num entities
#define NRC   500       // num relations
#define D1C   200
#define D2C   200
#define LLC   64        // literals
#define BN_EPS 1e-5f
#define LOG2E 1.4426950408889634f

// ws layout (floats):
//   xT   [D1][64]   @ 0       (bn0 output, transposed: xT[i*64+b])
//   rT   [D2][64]   @ 12800   (gathered relation rows, rT[k*64+b])
//   taT  [L ][64]   @ 25600   (2*(n_h - c)*s, transposed)
//   wT   [L ][64]   @ 29696   (nf[r] * exp2(-a^2), transposed)
//   sl   [L ]       @ 33792   (s[l] = sqrt(log2e/var_l[l]))
//   x2T  [D1][64]   @ 33856   (bn1 output, transposed)
//   y    [k][j][64] @ 46656   (per-k partials, r folded in)
#define WS_XT   0
#define WS_RT   12800
#define WS_AT   25600
#define WS_WT   29696
#define WS_SL   33792
#define WS_X2T  33856
#define WS_Y    46656

// ---------------------------------------------------------------------------
// Kernel A: gathers + bn0 + literal pre-transforms. Tiny; 3 blocks.
// ---------------------------------------------------------------------------
__global__ __launch_bounds__(256) void prep_kernel(
    const int* __restrict__ e1_idx, const int* __restrict__ r_idx,
    const float* __restrict__ E, const float* __restrict__ R,
    const float* __restrict__ lits, const float* __restrict__ c,
    const float* __restrict__ var_l, const float* __restrict__ nf,
    const float* __restrict__ bn0g, const float* __restrict__ bn0b,
    float* __restrict__ ws) {
  float* xT  = ws + WS_XT;
  float* rT  = ws + WS_RT;
  float* taT = ws + WS_AT;
  float* wT  = ws + WS_WT;
  float* sl  = ws + WS_SL;
  int tid = threadIdx.x;

  if (blockIdx.x == 0) {
    if (tid < D1C) {
      int j = tid;
      float sum = 0.f, sq = 0.f;
      for (int b = 0; b < BB; b++) {
        float e = E[e1_idx[b] * D1C + j];
        sum += e; sq += e * e;
      }
      float mean = sum * (1.f / 64.f);
      float var  = sq  * (1.f / 64.f) - mean * mean;
      float inv  = __builtin_amdgcn_rsqf(var + BN_EPS);
      float g    = bn0g[j] * inv;
      float be   = bn0b[j] - mean * g;
      for (int b = 0; b < BB; b++) {
        xT[j * 64 + b] = g * E[e1_idx[b] * D1C + j] + be;
      }
    }
  } else if (blockIdx.x == 1) {
    for (int idx = tid; idx < D2C * 64; idx += 256) {
      int k = idx >> 6, b = idx & 63;
      rT[idx] = R[r_idx[b] * D2C + k];
    }
  } else {
    // w*exp2(-(a-L)^2) = [w*exp2(-a^2)] * exp2(fma(2a, L, -L^2))
    for (int idx = tid; idx < LLC * 64; idx += 256) {
      int l = idx >> 6, b = idx & 63;
      float s = sqrtf(LOG2E / var_l[l]);
      float a = (lits[e1_idx[b] * LLC + l] - c[l]) * s;
      taT[idx] = a + a;
      wT[idx]  = nf[r_idx[b] * LLC + l] * __builtin_amdgcn_exp2f(-a * a);
    }
    if (tid < LLC) sl[tid] = sqrtf(LOG2E / var_l[tid]);
  }
}

// ---------------------------------------------------------------------------
// Stage 1 (unchanged R2 config, measured cheapest middle).
// ---------------------------------------------------------------------------
__global__ __launch_bounds__(128) void stage1_kernel(
    const float* __restrict__ W, const float* __restrict__ ws_in,
    float* __restrict__ y) {
  const float* xT = ws_in + WS_XT;
  const float* rT = ws_in + WS_RT;
  int k = blockIdx.x, jq = blockIdx.y;
  int lane = threadIdx.x & 63;
  int wid = __builtin_amdgcn_readfirstlane(threadIdx.x >> 6);
  int j0 = jq * 20 + wid * 10;

  float r = rT[k * 64 + lane];
  float acc[10];
#pragma unroll
  for (int jj = 0; jj < 10; jj++) acc[jj] = 0.f;

  const float* Wk = W + (k * D1C) * D1C + j0;
  for (int i = 0; i < D1C; i++) {
    float xv = xT[i * 64 + lane];
    const float* wr = Wk + i * D1C;
#pragma unroll
    for (int jj = 0; jj < 10; jj++) acc[jj] += xv * wr[jj];
  }

  float* yo = y + (k * D1C + j0) * 64 + lane;
#pragma unroll
  for (int jj = 0; jj < 10; jj++) yo[jj * 64] = r * acc[jj];
}

// ---------------------------------------------------------------------------
// Kernel C (unchanged): reduce y over k, bn1 over b -> x2T[j][b]
// ---------------------------------------------------------------------------
__global__ __launch_bounds__(256) void reduce_bn1_kernel(
    const float* __restrict__ y, const float* __restrict__ bn1g,
    const float* __restrict__ bn1b, float* __restrict__ ws) {
  float* x2T = ws + WS_X2T;
  int j = blockIdx.x;
  int tid = threadIdx.x, b = tid & 63, kq = tid >> 6;

  float s = 0.f;
  const float* yp = y + (kq * 50 * D1C + j) * 64 + b;
  for (int k = 0; k < 50; k++) s += yp[k * D1C * 64];

  __shared__ float part[256];
  part[tid] = s;
  __syncthreads();
  if (tid < 64) {
    float v = part[tid] + part[64 + tid] + part[128 + tid] + part[192 + tid];
    float sum = v, sq = v * v;
#pragma unroll
    for (int o = 32; o > 0; o >>= 1) {
      sum += __shfl_xor(sum, o, 64);
      sq  += __shfl_xor(sq,  o, 64);
    }
    float mean = sum * (1.f / 64.f);
    float var  = sq  * (1.f / 64.f) - mean * mean;
    float inv  = __builtin_amdgcn_rsqf(var + BN_EPS);
    float g    = bn1g[j] * inv;
    float be   = bn1b[j] - mean * g;
    x2T[j * 64 + tid] = g * v + be;
  }
}

// ---------------------------------------------------------------------------
// Final: out[b,n] = sigmoid( sum_j x2[b,j]E[n,j]
//                          + sum_l w'[b,l]*exp2(fma(2a[b,l], L[n,l], -L^2)) )
// grid 625, 256 thr. 2D REGISTER TILE: thread owns 4n x 4b (acc[16]).
//   lane&15 -> n-group (n1 = (lane&15)*4), wave*16 + (lane>>4)*4 -> b base.
// Per j: 4 ds_read_b32 (E) + 1 ds_read_b128 (x2) per 16 FMAs -> DS pipe
// (~20 cyc/j/wave) below VALU (32 cyc/j/wave): VALU-bound per-wave.
// LDS phased in a single 33.8KB arena (R4's proven 2-block footprint):
//   phase A: E quarter [64][53] identity copy + x2 quarter [50][64]
//   phase B: scaled lits [64][68] + ta/w halves [32][64] each
// ---------------------------------------------------------------------------
__global__ __launch_bounds__(256, 4) void final_kernel(
    const float* __restrict__ E, const float* __restrict__ lits,
    const float* __restrict__ ws, float* __restrict__ out) {
  const float* taT = ws + WS_AT;
  const float* wT  = ws + WS_WT;
  const float* sl  = ws + WS_SL;
  const float* x2T = ws + WS_X2T;

  __shared__ float SM[8448];          // 33792 B arena

  int n0 = blockIdx.x * 64;
  int tid = threadIdx.x;
  int lane = tid & 63;
  int wv = __builtin_amdgcn_readfirstlane(tid >> 6);
  int n1 = (lane & 15) * 4;           // local n base (0..60)
  int b1 = wv * 16 + (lane >> 4) * 4; // global b base (0..60)

  float acc[16];
#pragma unroll
  for (int t = 0; t < 16; t++) acc[t] = 0.f;

  float* Elds = SM;                   // [64][53] rows=n, cols=j-quarter
  float* Xlds = SM + 3392;            // [50][64] rows=j, cols=b

  // ---- score_l: 4 quarters of 50 j ----
  for (int q = 0; q < 4; q++) {
    __syncthreads();
    // stage E identity (no transpose): Elds[row][jj] = E[n0+row][q*50+jj]
    for (int idx = tid; idx < 1600; idx += 256) {
      int row = idx / 25, c2 = idx % 25;
      float2 v = *(const float2*)(E + (n0 + row) * D1C + q * 50 + c2 * 2);
      Elds[row * 53 + c2 * 2 + 0] = v.x;
      Elds[row * 53 + c2 * 2 + 1] = v.y;
    }
    // stage x2 quarter: straight float4 copy
    {
      const float4* src = (const float4*)(x2T + q * 3200);
      float4* dst = (float4*)Xlds;
      for (int idx = tid; idx < 800; idx += 256) dst[idx] = src[idx];
    }
    __syncthreads();
#pragma unroll 2
    for (int j = 0; j < 50; j++) {
      float e0 = Elds[(n1 + 0) * 53 + j];
      float e1 = Elds[(n1 + 1) * 53 + j];
      float e2 = Elds[(n1 + 2) * 53 + j];
      float e3 = Elds[(n1 + 3) * 53 + j];
      float4 xw = *(const float4*)(Xlds + j * 64 + b1);
      acc[ 0] += e0 * xw.x;  acc[ 1] += e0 * xw.y;
      acc[ 2] += e0 * xw.z;  acc[ 3] += e0 * xw.w;
      acc[ 4] += e1 * xw.x;  acc[ 5] += e1 * xw.y;
      acc[ 6] += e1 * xw.z;  acc[ 7] += e1 * xw.w;
      acc[ 8] += e2 * xw.x;  acc[ 9] += e2 * xw.y;
      acc[10] += e2 * xw.z;  acc[11] += e2 * xw.w;
      acc[12] += e3 * xw.x;  acc[13] += e3 * xw.y;
      acc[14] += e3 * xw.z;  acc[15] += e3 * xw.w;
    }
  }

  // ---- phase B: score_n ----
  float* Llds  = SM;                  // [64][68] rows=l, cols=n
  float* TAlds = SM + 4352;           // [32][64] rows=l-half, cols=b
  float* Wlds  = SM + 6400;           // [32][64]

  __syncthreads();                    // phase-A reads done
  // stage scaled literals, transposed: Llds[l][row] = lits[n0+row][l]*sl[l]
  for (int idx = tid; idx < 1024; idx += 256) {
    int row = idx >> 4, c4 = idx & 15;
    float4 v = *(const float4*)(lits + (n0 + row) * LLC + c4 * 4);
    int l = c4 * 4;
    Llds[(l + 0) * 68 + row] = v.x * sl[l + 0];
    Llds[(l + 1) * 68 + row] = v.y * sl[l + 1];
    Llds[(l + 2) * 68 + row] = v.z * sl[l + 2];
    Llds[(l + 3) * 68 + row] = v.w * sl[l + 3];
  }

  for (int h = 0; h < 2; h++) {
    if (h) __syncthreads();           // protect TA/W restage
    {
      const float4* ta4 = (const float4*)(taT + h * 2048);
      const float4* w4s = (const float4*)(wT + h * 2048);
      float4* dta = (float4*)TAlds;
      float4* dw  = (float4*)Wlds;
      for (int idx = tid; idx < 512; idx += 256) {
        dta[idx] = ta4[idx];
        dw[idx]  = w4s[idx];
      }
    }
    __syncthreads();
    for (int ll = 0; ll < 32; ll++) {
      int l = h * 32 + ll;
      float4 Lv = *(const float4*)(Llds + l * 68 + n1);
      float4 ta = *(const float4*)(TAlds + ll * 64 + b1);
      float4 wv4 = *(const float4*)(Wlds + ll * 64 + b1);
      float nl0 = -Lv.x * Lv.x, nl1 = -Lv.y * Lv.y;
      float nl2 = -Lv.z * Lv.z, nl3 = -Lv.w * Lv.w;
      acc[ 0] += wv4.x * __builtin_amdgcn_exp2f(__builtin_fmaf(ta.x, Lv.x, nl0));
      acc[ 1] += wv4.y * __builtin_amdgcn_exp2f(__builtin_fmaf(ta.y, Lv.x, nl0));
      acc[ 2] += wv4.z * __builtin_amdgcn_exp2f(__builtin_fmaf(ta.z, Lv.x, nl0));
      acc[ 3] += wv4.w * __builtin_amdgcn_exp2f(__builtin_fmaf(ta.w, Lv.x, nl0));
      acc[ 4] += wv4.x * __builtin_amdgcn_exp2f(__builtin_fmaf(ta.x, Lv.y, nl1));
      acc[ 5] += wv4.y * __builtin_amdgcn_exp2f(__builtin_fmaf(ta.y, Lv.y, nl1));
      acc[ 6] += wv4.z * __builtin_amdgcn_exp2f(__builtin_fmaf(ta.z, Lv.y, nl1));
      acc[ 7] += wv4.w * __builtin_amdgcn_exp2f(__builtin_fmaf(ta.w, Lv.y, nl1));
      acc[ 8] += wv4.x * __builtin_amdgcn_exp2f(__builtin_fmaf(ta.x, Lv.z, nl2));
      acc[ 9] += wv4.y * __builtin_amdgcn_exp2f(__builtin_fmaf(ta.y, Lv.z, nl2));
      acc[10] += wv4.z * __builtin_amdgcn_exp2f(__builtin_fmaf(ta.z, Lv.z, nl2));
      acc[11] += wv4.w * __builtin_amdgcn_exp2f(__builtin_fmaf(ta.w, Lv.z, nl2));
      acc[12] += wv4.x * __builtin_amdgcn_exp2f(__builtin_fmaf(ta.x, Lv.w, nl3));
      acc[13] += wv4.y * __builtin_amdgcn_exp2f(__builtin_fmaf(ta.y, Lv.w, nl3));
      acc[14] += wv4.z * __builtin_amdgcn_exp2f(__builtin_fmaf(ta.z, Lv.w, nl3));
      acc[15] += wv4.w * __builtin_amdgcn_exp2f(__builtin_fmaf(ta.w, Lv.w, nl3));
    }
  }

  // ---- sigmoid + dwordx4 stores (4 contiguous n per b-row) ----
#pragma unroll
  for (int bbb = 0; bbb < 4; bbb++) {
    float4 o;
    float s0 = acc[ 0 + bbb], s1 = acc[ 4 + bbb];
    float s2 = acc[ 8 + bbb], s3 = acc[12 + bbb];
    o.x = __builtin_amdgcn_rcpf(1.f + __builtin_amdgcn_exp2f(-LOG2E * s0));
    o.y = __builtin_amdgcn_rcpf(1.f + __builtin_amdgcn_exp2f(-LOG2E * s1));
    o.z = __builtin_amdgcn_rcpf(1.f + __builtin_amdgcn_exp2f(-LOG2E * s2));
    o.w = __builtin_amdgcn_rcpf(1.f + __builtin_amdgcn_exp2f(-LOG2E * s3));
    *(float4*)(out + (size_t)(b1 + bbb) * NEC + n0 + n1) = o;
  }
}

// ---------------------------------------------------------------------------
extern "C" void kernel_launch(void* const* d_in, const int* in_sizes, int n_in,
                              void* d_out, int out_size, void* d_ws, size_t ws_size,
                              hipStream_t stream) {
  (void)in_sizes; (void)n_in; (void)out_size; (void)ws_size;
  const int*   e1    = (const int*)d_in[0];
  const int*   ri    = (const int*)d_in[1];
  const float* E     = (const float*)d_in[2];
  const float* R     = (const float*)d_in[3];
  const float* W     = (const float*)d_in[4];
  const float* lits  = (const float*)d_in[5];
  const float* c     = (const float*)d_in[6];
  const float* var_l = (const float*)d_in[7];
  const float* nf    = (const float*)d_in[8];
  const float* bn0g  = (const float*)d_in[9];
  const float* bn0b  = (const float*)d_in[10];
  const float* bn1g  = (const float*)d_in[11];
  const float* bn1b  = (const float*)d_in[12];
  float* out = (float*)d_out;
  float* ws  = (float*)d_ws;
  float* y   = ws + WS_Y;

  prep_kernel<<<3, 256, 0, stream>>>(e1, ri, E, R, lits, c, var_l, nf,
                                     bn0g, bn0b, ws);
  stage1_kernel<<<dim3(200, 10), 128, 0, stream>>>(W, ws, y);
  reduce_bn1_kernel<<<200, 256, 0, stream>>>(y, bn1g, bn1b, ws);
  final_kernel<<<625, 256, 0, stream>>>(E, lits, ws, out);
}

// Round 9
// 196.760 us; speedup vs baseline: 5.2577x; 1.1363x over previous
//
#include <hip/hip_runtime.h>
#include <math.h>

// Problem constants
#define BB    64
#define NEC   40000
#define NRC   500
#define D1C   200
#define D2C   200
#define LLC   64
#define BN_EPS 1e-5f
#define LOG2E 1.4426950408889634f

// ws layout (floats):
//   xT    [D1][64]        @ 0      (bn0 output, transposed)
//   rT    [D2][64]        @ 12800  (gathered relation rows)
//   taP   [L][64]         @ 25600  (2a, b-permuted: bp=(b&15)*4+(b>>4))
//   wP    [L][64]         @ 29696  (w*exp2(-a^2), b-permuted)
//   sl    [L]             @ 33792
//   x2Bh  bf16[64][256]   @ 33856  (bn1 out, b-major, K zero-padded, hi)
//   x2Bl  bf16[64][256]   @ 42048  (lo part)
//   y     [k][j][64]      @ 50240  (stage-1 partials)
#define WS_XT    0
#define WS_RT    12800
#define WS_TAP   25600
#define WS_WP    29696
#define WS_SL    33792
#define WS_X2BH  33856
#define WS_X2BL  42048
#define WS_Y     50240

typedef short s8v __attribute__((ext_vector_type(8)));   // 8 bf16 (4 VGPRs)
typedef float f4v __attribute__((ext_vector_type(4)));   // MFMA acc

__device__ __forceinline__ unsigned short bf16_rne(float x) {
  unsigned b = __float_as_uint(x);
  unsigned r = b + 0x7FFFu + ((b >> 16) & 1u);
  return (unsigned short)(r >> 16);
}
__device__ __forceinline__ void split2(float x, unsigned short& h,
                                       unsigned short& l) {
  h = bf16_rne(x);
  float hf = __uint_as_float(((unsigned)h) << 16);
  l = bf16_rne(x - hf);
}

// ---------------------------------------------------------------------------
// Kernel A: gathers + bn0 + literal pre-transforms + x2B zero-init. 4 blocks.
// ---------------------------------------------------------------------------
__global__ __launch_bounds__(256) void prep_kernel(
    const int* __restrict__ e1_idx, const int* __restrict__ r_idx,
    const float* __restrict__ E, const float* __restrict__ R,
    const float* __restrict__ lits, const float* __restrict__ c,
    const float* __restrict__ var_l, const float* __restrict__ nf,
    const float* __restrict__ bn0g, const float* __restrict__ bn0b,
    float* __restrict__ ws) {
  float* xT  = ws + WS_XT;
  float* rT  = ws + WS_RT;
  float* taP = ws + WS_TAP;
  float* wP  = ws + WS_WP;
  float* sl  = ws + WS_SL;
  int tid = threadIdx.x;

  if (blockIdx.x == 0) {
    if (tid < D1C) {
      int j = tid;
      float sum = 0.f, sq = 0.f;
      for (int b = 0; b < BB; b++) {
        float e = E[e1_idx[b] * D1C + j];
        sum += e; sq += e * e;
      }
      float mean = sum * (1.f / 64.f);
      float var  = sq  * (1.f / 64.f) - mean * mean;
      float inv  = __builtin_amdgcn_rsqf(var + BN_EPS);
      float g    = bn0g[j] * inv;
      float be   = bn0b[j] - mean * g;
      for (int b = 0; b < BB; b++) {
        xT[j * 64 + b] = g * E[e1_idx[b] * D1C + j] + be;
      }
    }
  } else if (blockIdx.x == 1) {
    for (int idx = tid; idx < D2C * 64; idx += 256) {
      int k = idx >> 6, b = idx & 63;
      rT[idx] = R[r_idx[b] * D2C + k];
    }
  } else if (blockIdx.x == 2) {
    // w*exp2(-(a-L)^2) = [w*exp2(-a^2)] * exp2(fma(2a, L, -L^2))
    // stored with b-permutation bp = (b&15)*4 + (b>>4) to match MFMA C-layout
    for (int idx = tid; idx < LLC * 64; idx += 256) {
      int l = idx >> 6, b = idx & 63;
      float s = sqrtf(LOG2E / var_l[l]);
      float a = (lits[e1_idx[b] * LLC + l] - c[l]) * s;
      int bp = (b & 15) * 4 + (b >> 4);
      taP[l * 64 + bp] = a + a;
      wP[l * 64 + bp]  = nf[r_idx[b] * LLC + l] * __builtin_amdgcn_exp2f(-a * a);
    }
    if (tid < LLC) sl[tid] = sqrtf(LOG2E / var_l[tid]);
  } else {
    // zero x2Bh/x2Bl (covers K padding 200..255)
    unsigned* z = (unsigned*)(ws + WS_X2BH);
    for (int i = tid; i < 16384; i += 256) z[i] = 0u;
  }
}

// ---------------------------------------------------------------------------
// Stage 1 (unchanged R2 config, measured cheapest middle).
// ---------------------------------------------------------------------------
__global__ __launch_bounds__(128) void stage1_kernel(
    const float* __restrict__ W, const float* __restrict__ ws_in,
    float* __restrict__ y) {
  const float* xT = ws_in + WS_XT;
  const float* rT = ws_in + WS_RT;
  int k = blockIdx.x, jq = blockIdx.y;
  int lane = threadIdx.x & 63;
  int wid = __builtin_amdgcn_readfirstlane(threadIdx.x >> 6);
  int j0 = jq * 20 + wid * 10;

  float r = rT[k * 64 + lane];
  float acc[10];
#pragma unroll
  for (int jj = 0; jj < 10; jj++) acc[jj] = 0.f;

  const float* Wk = W + (k * D1C) * D1C + j0;
  for (int i = 0; i < D1C; i++) {
    float xv = xT[i * 64 + lane];
    const float* wr = Wk + i * D1C;
#pragma unroll
    for (int jj = 0; jj < 10; jj++) acc[jj] += xv * wr[jj];
  }

  float* yo = y + (k * D1C + j0) * 64 + lane;
#pragma unroll
  for (int jj = 0; jj < 10; jj++) yo[jj * 64] = r * acc[jj];
}

// ---------------------------------------------------------------------------
// Kernel C: reduce y over k, bn1 over b -> split-bf16 x2B (b-major, K-padded)
// ---------------------------------------------------------------------------
__global__ __launch_bounds__(256) void reduce_bn1_kernel(
    const float* __restrict__ y, const float* __restrict__ bn1g,
    const float* __restrict__ bn1b, float* __restrict__ ws) {
  int j = blockIdx.x;
  int tid = threadIdx.x, b = tid & 63, kq = tid >> 6;

  float s = 0.f;
  const float* yp = y + (kq * 50 * D1C + j) * 64 + b;
  for (int k = 0; k < 50; k++) s += yp[k * D1C * 64];

  __shared__ float part[256];
  part[tid] = s;
  __syncthreads();
  if (tid < 64) {
    float v = part[tid] + part[64 + tid] + part[128 + tid] + part[192 + tid];
    float sum = v, sq = v * v;
#pragma unroll
    for (int o = 32; o > 0; o >>= 1) {
      sum += __shfl_xor(sum, o, 64);
      sq  += __shfl_xor(sq,  o, 64);
    }
    float mean = sum * (1.f / 64.f);
    float var  = sq  * (1.f / 64.f) - mean * mean;
    float inv  = __builtin_amdgcn_rsqf(var + BN_EPS);
    float g    = bn1g[j] * inv;
    float be   = bn1b[j] - mean * g;
    float xv   = g * v + be;
    unsigned short h, l;
    split2(xv, h, l);
    unsigned short* xh = (unsigned short*)(ws + WS_X2BH);
    unsigned short* xl = (unsigned short*)(ws + WS_X2BL);
    xh[tid * 256 + j] = h;
    xl[tid * 256 + j] = l;
  }
}

// ---------------------------------------------------------------------------
// Final: score_l via split-bf16 MFMA 16x16x32; score_n via R8 loop on the
// MFMA C-fragment mapping. grid 625, 256 thr = 4 waves.
//   wave w owns C rows [16w,16w+16); 4 col-tiles t -> b = 16t + (lane&15).
//   C elem: n = n0+16w+4*quad+reg (quad=lane>>4), b = 16t+ln.
// K = 200 padded to 256, staged in 4 slabs of 64 (Ah/Al from E with on-the-
// fly split-bf16; Bh/Bl straight copy of precomputed x2B). Row stride 72
// bf16 -> frag b128 reads 2-way bank aliasing (free), 16B-aligned.
// ---------------------------------------------------------------------------
__global__ __launch_bounds__(256, 2) void final_kernel(
    const float* __restrict__ E, const float* __restrict__ lits,
    const float* __restrict__ ws, float* __restrict__ out) {
  const float* taP = ws + WS_TAP;
  const float* wP  = ws + WS_WP;
  const float* sl  = ws + WS_SL;
  const unsigned short* x2bh = (const unsigned short*)(ws + WS_X2BH);
  const unsigned short* x2bl = (const unsigned short*)(ws + WS_X2BL);

  __shared__ float SM[9216];                 // 36864 B arena
  unsigned short* Ah = (unsigned short*)SM;  // [64][72] bf16
  unsigned short* Al = Ah + 4608;
  unsigned short* Bh = Ah + 9216;
  unsigned short* Bl = Ah + 13824;

  int n0 = blockIdx.x * 64;
  int tid = threadIdx.x;
  int lane = tid & 63;
  int w = __builtin_amdgcn_readfirstlane(tid >> 6);
  int ln = lane & 15;
  int quad = lane >> 4;

  f4v acc[4];
#pragma unroll
  for (int t = 0; t < 4; t++) acc[t] = (f4v){0.f, 0.f, 0.f, 0.f};

  // ---- score_l: 4 K-slabs of 64 ----
  for (int q = 0; q < 4; q++) {
    int k0 = q * 64;
    __syncthreads();
    // stage E slab -> Ah/Al (split-bf16 on the fly)
#pragma unroll
    for (int it = 0; it < 4; it++) {
      int idx = tid + it * 256;
      int row = idx >> 4, c4 = idx & 15, cc = c4 * 4;
      float4 v = make_float4(0.f, 0.f, 0.f, 0.f);
      if (k0 + cc < 200) v = *(const float4*)(E + (n0 + row) * D1C + k0 + cc);
      unsigned short h0, l0, h1, l1, h2, l2, h3, l3;
      split2(v.x, h0, l0); split2(v.y, h1, l1);
      split2(v.z, h2, l2); split2(v.w, h3, l3);
      *(ushort4*)(Ah + row * 72 + cc) = make_ushort4(h0, h1, h2, h3);
      *(ushort4*)(Al + row * 72 + cc) = make_ushort4(l0, l1, l2, l3);
    }
    // stage x2B slab -> Bh/Bl (straight copy; K-pad already zeroed)
#pragma unroll
    for (int it = 0; it < 4; it++) {
      int idx = tid + it * 256;
      int row = idx >> 4, c4 = idx & 15;
      *(ushort4*)(Bh + row * 72 + c4 * 4) =
          *(const ushort4*)(x2bh + row * 256 + k0 + c4 * 4);
      *(ushort4*)(Bl + row * 72 + c4 * 4) =
          *(const ushort4*)(x2bl + row * 256 + k0 + c4 * 4);
    }
    __syncthreads();

    const unsigned short* Ab  = Ah + (16 * w + ln) * 72 + quad * 8;
    const unsigned short* Alb = Al + (16 * w + ln) * 72 + quad * 8;
#pragma unroll
    for (int ks = 0; ks < 64; ks += 32) {
      s8v ah = *(const s8v*)(Ab + ks);
      s8v al = *(const s8v*)(Alb + ks);
#pragma unroll
      for (int t = 0; t < 4; t++) {
        s8v bh = *(const s8v*)(Bh + (16 * t + ln) * 72 + quad * 8 + ks);
        s8v bl = *(const s8v*)(Bl + (16 * t + ln) * 72 + quad * 8 + ks);
        acc[t] = __builtin_amdgcn_mfma_f32_16x16x32_bf16(ah, bh, acc[t], 0, 0, 0);
        acc[t] = __builtin_amdgcn_mfma_f32_16x16x32_bf16(al, bh, acc[t], 0, 0, 0);
        acc[t] = __builtin_amdgcn_mfma_f32_16x16x32_bf16(ah, bl, acc[t], 0, 0, 0);
      }
    }
  }

  // ---- phase B: score_n on the C-fragment mapping ----
  float* Llds = SM;           // [64][68] scaled lits, rows=l, cols=n-local
  float* TAl  = SM + 4352;    // [32][64] ta half (b-permuted)
  float* Wl   = SM + 6400;    // [32][64]
  int nlb = 16 * w + 4 * quad;

  __syncthreads();
#pragma unroll
  for (int it = 0; it < 4; it++) {
    int idx = tid + it * 256;
    int row = idx >> 4, c4 = idx & 15;
    float4 v = *(const float4*)(lits + (n0 + row) * LLC + c4 * 4);
    int l = c4 * 4;
    Llds[(l + 0) * 68 + row] = v.x * sl[l + 0];
    Llds[(l + 1) * 68 + row] = v.y * sl[l + 1];
    Llds[(l + 2) * 68 + row] = v.z * sl[l + 2];
    Llds[(l + 3) * 68 + row] = v.w * sl[l + 3];
  }

  for (int h = 0; h < 2; h++) {
    __syncthreads();          // h=0: Llds staged; h=1: previous reads done
#pragma unroll
    for (int it = 0; it < 2; it++) {
      int idx = tid + it * 256;
      ((float4*)TAl)[idx] = ((const float4*)(taP + h * 2048))[idx];
      ((float4*)Wl)[idx]  = ((const float4*)(wP  + h * 2048))[idx];
    }
    __syncthreads();
    for (int ll = 0; ll < 32; ll++) {
      float4 Lv = *(const float4*)(Llds + (h * 32 + ll) * 68 + nlb);
      float4 ta = *(const float4*)(TAl + ll * 64 + 4 * ln);
      float4 wv = *(const float4*)(Wl  + ll * 64 + 4 * ln);
      float Lc[4]  = {Lv.x, Lv.y, Lv.z, Lv.w};
      float tac[4] = {ta.x, ta.y, ta.z, ta.w};
      float wvc[4] = {wv.x, wv.y, wv.z, wv.w};
      float n2[4];
#pragma unroll
      for (int r = 0; r < 4; r++) n2[r] = -Lc[r] * Lc[r];
#pragma unroll
      for (int t = 0; t < 4; t++) {
#pragma unroll
        for (int r = 0; r < 4; r++) {
          acc[t][r] += wvc[t] *
              __builtin_amdgcn_exp2f(__builtin_fmaf(tac[t], Lc[r], n2[r]));
        }
      }
    }
  }

  // ---- sigmoid + float4 stores (4 consecutive n per b-row) ----
#pragma unroll
  for (int t = 0; t < 4; t++) {
    float4 o;
    o.x = __builtin_amdgcn_rcpf(1.f + __builtin_amdgcn_exp2f(-LOG2E * acc[t][0]));
    o.y = __builtin_amdgcn_rcpf(1.f + __builtin_amdgcn_exp2f(-LOG2E * acc[t][1]));
    o.z = __builtin_amdgcn_rcpf(1.f + __builtin_amdgcn_exp2f(-LOG2E * acc[t][2]));
    o.w = __builtin_amdgcn_rcpf(1.f + __builtin_amdgcn_exp2f(-LOG2E * acc[t][3]));
    *(float4*)(out + (size_t)(16 * t + ln) * NEC + n0 + nlb) = o;
  }
}

// ---------------------------------------------------------------------------
extern "C" void kernel_launch(void* const* d_in, const int* in_sizes, int n_in,
                              void* d_out, int out_size, void* d_ws, size_t ws_size,
                              hipStream_t stream) {
  (void)in_sizes; (void)n_in; (void)out_size; (void)ws_size;
  const int*   e1    = (const int*)d_in[0];
  const int*   ri    = (const int*)d_in[1];
  const float* E     = (const float*)d_in[2];
  const float* R     = (const float*)d_in[3];
  const float* W     = (const float*)d_in[4];
  const float* lits  = (const float*)d_in[5];
  const float* c     = (const float*)d_in[6];
  const float* var_l = (const float*)d_in[7];
  const float* nf    = (const float*)d_in[8];
  const float* bn0g  = (const float*)d_in[9];
  const float* bn0b  = (const float*)d_in[10];
  const float* bn1g  = (const float*)d_in[11];
  const float* bn1b  = (const float*)d_in[12];
  float* out = (float*)d_out;
  float* ws  = (float*)d_ws;
  float* y   = ws + WS_Y;

  prep_kernel<<<4, 256, 0, stream>>>(e1, ri, E, R, lits, c, var_l, nf,
                                     bn0g, bn0b, ws);
  stage1_kernel<<<dim3(200, 10), 128, 0, stream>>>(W, ws, y);
  reduce_bn1_kernel<<<200, 256, 0, stream>>>(y, bn1g, bn1b, ws);
  final_kernel<<<625, 256, 0, stream>>>(E, lits, ws, out);
}